// Round 1
// baseline (92.606 us; speedup 1.0000x reference)
//
#include <hip/hip_runtime.h>

// 4-qubit / 3-layer VQC, B = 2^20.
//
// Identity (verified R4): with merged angle th_w = patch_w + params[0,w,0],
// each output is EXACTLY multilinear in t_w = (1, cos th_w, sin th_w):
//     o_w = sum T^w[a,b,c,d] t0_a t1_b t2_c t3_d
// Setup kernel simulates the batch-uniform remainder of the circuit on the
// 3^4 grid th in {0, pi/2, pi} and inverts the evaluation map -> T.
//
// R6 changes vs R5 (theory: main was T-table-load bound, ~30 us of the
// 36 us non-fill time; roofline for main is ~5.3 us of HBM traffic):
//  - T staged in LDS once per block (1.3 KB); inner loop reads are
//    uniform-address ds_read broadcasts (no L1 vector traffic, no reliance
//    on the compiler scalarizing uniform global loads into s_loads).
//  - 2 batch elements per thread, interleaved by blockDim so patch loads
//    and out stores stay perfectly coalesced; halves per-element T reads.
//  - setup launched with 384 threads so each inversion mode is one pass.

typedef float v2f __attribute__((ext_vector_type(2)));

// ws layout: [0..161]   pairs (T0[pos], T1[pos]) for pos = 0..80
//            [162..323] pairs (T2[pos], T3[pos])
// pos = 9*(3*d0+d1) + (3*d2+d3), digit d in {0,1,2} <-> basis (1, cos, sin)
__global__ void vqc_setup(const float* __restrict__ params,
                          float* __restrict__ ws) {
    __shared__ float trig[12][4];   // (cy, sy, cz, sz) half-angle per (l,w)
    __shared__ float bufA[81][4];
    __shared__ float bufB[81][4];
    const int tid = threadIdx.x;

    if (tid < 12) {
        float s, c;
        __sincosf(0.5f * params[tid * 2 + 0], &s, &c);
        trig[tid][0] = c; trig[tid][1] = s;
        __sincosf(0.5f * params[tid * 2 + 1], &s, &c);
        trig[tid][2] = c; trig[tid][3] = s;
    }
    __syncthreads();

    if (tid < 81) {
        const int d0 = tid / 27, d1 = (tid / 9) % 3, d2 = (tid / 3) % 3, d3 = tid % 3;
        const float chalf[3] = {1.0f, 0.70710678118654752f, 0.0f};
        const float shalf[3] = {0.0f, 0.70710678118654752f, 1.0f};
        const float ch[4] = {chalf[d0], chalf[d1], chalf[d2], chalf[d3]};
        const float sh[4] = {shalf[d0], shalf[d1], shalf[d2], shalf[d3]};

        // initial product state (grid angle already includes layer-0 RY)
        float re[16], im[16];
#pragma unroll
        for (int k = 0; k < 16; ++k) {
            float a = ((k >> 3) & 1) ? sh[0] : ch[0];
            a *= ((k >> 2) & 1) ? sh[1] : ch[1];
            a *= ((k >> 1) & 1) ? sh[2] : ch[2];
            a *= (k & 1) ? sh[3] : ch[3];
            re[k] = a; im[k] = 0.0f;
        }

        // ---- layer 0: RZ only ----
#pragma unroll
        for (int w = 0; w < 4; ++w) {
            const int m = 8 >> w;
            const float cz = trig[w][2], sz = trig[w][3];
#pragma unroll
            for (int k = 0; k < 16; ++k) {
                const float r = re[k], q = im[k];
                if (k & m) { re[k] = r * cz - q * sz; im[k] = q * cz + r * sz; }
                else       { re[k] = r * cz + q * sz; im[k] = q * cz - r * sz; }
            }
        }
#pragma unroll
        for (int w = 0; w < 3; ++w) {
            const int cm = 8 >> w, tm = 4 >> w;
#pragma unroll
            for (int b = 0; b < 16; ++b) {
                if ((b & cm) && !(b & tm)) {
                    const int j = b | tm;
                    float t = re[b]; re[b] = re[j]; re[j] = t;
                    t = im[b]; im[b] = im[j]; im[j] = t;
                }
            }
        }

        // ---- layers 1, 2 (layer-2 RZ dropped: probability-invariant) ----
#pragma unroll
        for (int l = 1; l < 3; ++l) {
#pragma unroll
            for (int w = 0; w < 4; ++w) {
                const int m = 8 >> w, g = l * 4 + w;
                const float cy = trig[g][0], sy = trig[g][1];
#pragma unroll
                for (int b = 0; b < 16; ++b) {
                    if (b & m) continue;
                    const int j = b | m;
                    const float r0 = re[b], r1 = re[j];
                    const float i0 = im[b], i1 = im[j];
                    re[b] = cy * r0 - sy * r1;  re[j] = sy * r0 + cy * r1;
                    im[b] = cy * i0 - sy * i1;  im[j] = sy * i0 + cy * i1;
                }
                if (l != 2) {
                    const float cz = trig[g][2], sz = trig[g][3];
#pragma unroll
                    for (int k = 0; k < 16; ++k) {
                        const float r = re[k], q = im[k];
                        if (k & m) { re[k] = r * cz - q * sz; im[k] = q * cz + r * sz; }
                        else       { re[k] = r * cz + q * sz; im[k] = q * cz - r * sz; }
                    }
                }
            }
#pragma unroll
            for (int w = 0; w < 3; ++w) {
                const int cm = 8 >> w, tm = 4 >> w;
#pragma unroll
                for (int b = 0; b < 16; ++b) {
                    if ((b & cm) && !(b & tm)) {
                        const int j = b | tm;
                        float t = re[b]; re[b] = re[j]; re[j] = t;
                        t = im[b]; im[b] = im[j]; im[j] = t;
                    }
                }
            }
        }

        float ev0 = 0.f, ev1 = 0.f, ev2 = 0.f, ev3 = 0.f;
#pragma unroll
        for (int k = 0; k < 16; ++k) {
            const float pk = re[k] * re[k] + im[k] * im[k];
            ev0 += (k & 8) ? -pk : pk;
            ev1 += (k & 4) ? -pk : pk;
            ev2 += (k & 2) ? -pk : pk;
            ev3 += (k & 1) ? -pk : pk;
        }
        bufA[tid][0] = ev0; bufA[tid][1] = ev1;
        bufA[tid][2] = ev2; bufA[tid][3] = ev3;
    }
    __syncthreads();

    // ---- invert evaluation map mode-by-mode ----
    // nodes {0, pi/2, pi} -> rows (1,1,0),(1,0,1),(1,-1,0);
    // Minv = [[.5,0,.5],[.5,0,-.5],[-.5,1,-.5]]
    const float Minv[3][3] = {{0.5f, 0.0f, 0.5f},
                              {0.5f, 0.0f, -0.5f},
                              {-0.5f, 1.0f, -0.5f}};
    const int strides[4] = {27, 9, 3, 1};
#pragma unroll
    for (int mo = 0; mo < 4; ++mo) {
        const int st = strides[mo];
        float (*src)[4] = (mo & 1) ? bufB : bufA;
        float (*dst)[4] = (mo & 1) ? bufA : bufB;
        for (int idx = tid; idx < 324; idx += blockDim.x) {
            const int w = idx & 3, pos = idx >> 2;
            const int dm = (pos / st) % 3;
            const int base = pos - dm * st;
            const float v = Minv[dm][0] * src[base][w]
                          + Minv[dm][1] * src[base + st][w]
                          + Minv[dm][2] * src[base + 2 * st][w];
            if (mo == 3) {
                // interleave: (T0,T1) pairs then (T2,T3) pairs
                const int half = (w >> 1);          // 0 for T0/T1, 1 for T2/T3
                ws[half * 162 + pos * 2 + (w & 1)] = v;
            } else {
                dst[pos][w] = v;
            }
        }
        __syncthreads();
    }
}

__global__ __launch_bounds__(256) void vqc_main(const float* __restrict__ patch,
                                                const float* __restrict__ params,
                                                const float* __restrict__ ws,
                                                float* __restrict__ out,
                                                const int B) {
    // Stage the whole T table in LDS once per block: 162 v2f = 1296 B.
    // All lanes of a wave read the SAME LDS address in the inner loop ->
    // hardware broadcast, zero bank conflicts, no global/L1 traffic.
    __shared__ __align__(16) v2f Tsh[162];
    const int tid = threadIdx.x;
    if (tid < 162) Tsh[tid] = reinterpret_cast<const v2f*>(ws)[tid];

    // uniform scalars (compiler keeps these in SGPRs)
    const float q0 = params[0], q1 = params[2], q2 = params[4], q3 = params[6];
    __syncthreads();

    // Two elements per thread, interleaved by blockDim so both the patch
    // loads and the out stores are perfectly dense across the wave.
    const int iA = blockIdx.x * (blockDim.x * 2) + tid;
    const int iB = iA + blockDim.x;
    if (iA >= B) return;
    const bool haveB = (iB < B);

    const float4 pa = reinterpret_cast<const float4*>(patch)[iA];
    const float4 pb = haveB ? reinterpret_cast<const float4*>(patch)[iB] : pa;

    float ca0, sa0, ca1, sa1, ca2, sa2, ca3, sa3;
    __sincosf(pa.x + q0, &sa0, &ca0);
    __sincosf(pa.y + q1, &sa1, &ca1);
    __sincosf(pa.z + q2, &sa2, &ca2);
    __sincosf(pa.w + q3, &sa3, &ca3);
    float cb0, sb0, cb1, sb1, cb2, sb2, cb3, sb3;
    __sincosf(pb.x + q0, &sb0, &cb0);
    __sincosf(pb.y + q1, &sb1, &cb1);
    __sincosf(pb.z + q2, &sb2, &cb2);
    __sincosf(pb.w + q3, &sb3, &cb3);

    float va01[9], va23[9], vb01[9], vb23[9];
    va01[0] = 1.0f; va01[1] = ca1;       va01[2] = sa1;
    va01[3] = ca0;  va01[4] = ca0 * ca1; va01[5] = ca0 * sa1;
    va01[6] = sa0;  va01[7] = sa0 * ca1; va01[8] = sa0 * sa1;
    va23[0] = 1.0f; va23[1] = ca3;       va23[2] = sa3;
    va23[3] = ca2;  va23[4] = ca2 * ca3; va23[5] = ca2 * sa3;
    va23[6] = sa2;  va23[7] = sa2 * ca3; va23[8] = sa2 * sa3;
    vb01[0] = 1.0f; vb01[1] = cb1;       vb01[2] = sb1;
    vb01[3] = cb0;  vb01[4] = cb0 * cb1; vb01[5] = cb0 * sb1;
    vb01[6] = sb0;  vb01[7] = sb0 * cb1; vb01[8] = sb0 * sb1;
    vb23[0] = 1.0f; vb23[1] = cb3;       vb23[2] = sb3;
    vb23[3] = cb2;  vb23[4] = cb2 * cb3; vb23[5] = cb2 * sb3;
    vb23[6] = sb2;  vb23[7] = sb2 * cb3; vb23[8] = sb2 * sb3;

    const v2f* __restrict__ TA = Tsh;        // (T0,T1) pairs
    const v2f* __restrict__ TB = Tsh + 81;   // (T2,T3) pairs

    v2f oa01 = {0.f, 0.f}, oa23 = {0.f, 0.f};
    v2f ob01 = {0.f, 0.f}, ob23 = {0.f, 0.f};
#pragma unroll
    for (int a = 0; a < 9; ++a) {
        v2f ya01 = {0.f, 0.f}, ya23 = {0.f, 0.f};
        v2f yb01 = {0.f, 0.f}, yb23 = {0.f, 0.f};
#pragma unroll
        for (int b = 0; b < 9; ++b) {
            const v2f ta = TA[9 * a + b];    // ds_read broadcast, shared by
            const v2f tb = TB[9 * a + b];    // both batch elements
            ya01 += ta * va23[b];            // v_pk_fma_f32
            ya23 += tb * va23[b];
            yb01 += ta * vb23[b];
            yb23 += tb * vb23[b];
        }
        oa01 += va01[a] * ya01;  oa23 += va01[a] * ya23;
        ob01 += vb01[a] * yb01;  ob23 += vb01[a] * yb23;
    }

    reinterpret_cast<float4*>(out)[iA] = make_float4(oa01.x, oa01.y, oa23.x, oa23.y);
    if (haveB)
        reinterpret_cast<float4*>(out)[iB] = make_float4(ob01.x, ob01.y, ob23.x, ob23.y);
}

extern "C" void kernel_launch(void* const* d_in, const int* in_sizes, int n_in,
                              void* d_out, int out_size, void* d_ws, size_t ws_size,
                              hipStream_t stream) {
    const float* patch  = (const float*)d_in[0];
    const float* params = (const float*)d_in[1];
    float* out = (float*)d_out;
    float* ws  = (float*)d_ws;
    const int B = in_sizes[0] / 4;

    vqc_setup<<<1, 384, 0, stream>>>(params, ws);

    const int block = 256;
    const int elems_per_block = block * 2;
    const int grid = (B + elems_per_block - 1) / elems_per_block;
    vqc_main<<<grid, block, 0, stream>>>(patch, params, ws, out, B);
}

// Round 2
// 78.323 us; speedup vs baseline: 1.1824x; 1.1824x over previous
//
#include <hip/hip_runtime.h>

// 4-qubit / 3-layer VQC, B = 2^20.
//
// Identity (verified R4): with merged angle th_w = patch_w + params[0,w,0],
// each output is EXACTLY multilinear in t_w = (1, cos th_w, sin th_w):
//     o_w = sum T^w[a,b,c,d] t0_a t1_b t2_c t3_d
// Setup kernel simulates the batch-uniform remainder of the circuit on the
// 3^4 grid th in {0, pi/2, pi} and inverts the evaluation map -> T.
//
// R7: revert R6's LDS staging (post-mortem: uniform ds_read broadcasts are
// issue-serialized on the per-CU LDS pipe: 5.2k ds_read/CU x ~5cyc = +11us,
// matching the measured +12.7us regression). Back to R5's uniform global
// loads (L1/scalar path), ONE change on top:
//  - T stored as QUADS (T0,T1,T2,T3)[pos] -> inner loop issues 81
//    dwordx4 loads per wave-element instead of 162 dwordx2 -> halves the
//    memory-issue count. The two v_pk_fma_f32 consume the quad's reg pairs
//    [n:n+1], [n+2:n+3] directly.

typedef float v2f __attribute__((ext_vector_type(2)));
typedef float v4f __attribute__((ext_vector_type(4)));

// ws layout: quad (T0,T1,T2,T3)[pos] at ws[4*pos .. 4*pos+3], pos = 0..80
// pos = 9*(3*d0+d1) + (3*d2+d3), digit d in {0,1,2} <-> basis (1, cos, sin)
__global__ void vqc_setup(const float* __restrict__ params,
                          float* __restrict__ ws) {
    __shared__ float trig[12][4];   // (cy, sy, cz, sz) half-angle per (l,w)
    __shared__ float bufA[81][4];
    __shared__ float bufB[81][4];
    const int tid = threadIdx.x;

    if (tid < 12) {
        float s, c;
        __sincosf(0.5f * params[tid * 2 + 0], &s, &c);
        trig[tid][0] = c; trig[tid][1] = s;
        __sincosf(0.5f * params[tid * 2 + 1], &s, &c);
        trig[tid][2] = c; trig[tid][3] = s;
    }
    __syncthreads();

    if (tid < 81) {
        const int d0 = tid / 27, d1 = (tid / 9) % 3, d2 = (tid / 3) % 3, d3 = tid % 3;
        const float chalf[3] = {1.0f, 0.70710678118654752f, 0.0f};
        const float shalf[3] = {0.0f, 0.70710678118654752f, 1.0f};
        const float ch[4] = {chalf[d0], chalf[d1], chalf[d2], chalf[d3]};
        const float sh[4] = {shalf[d0], shalf[d1], shalf[d2], shalf[d3]};

        // initial product state (grid angle already includes layer-0 RY)
        float re[16], im[16];
#pragma unroll
        for (int k = 0; k < 16; ++k) {
            float a = ((k >> 3) & 1) ? sh[0] : ch[0];
            a *= ((k >> 2) & 1) ? sh[1] : ch[1];
            a *= ((k >> 1) & 1) ? sh[2] : ch[2];
            a *= (k & 1) ? sh[3] : ch[3];
            re[k] = a; im[k] = 0.0f;
        }

        // ---- layer 0: RZ only ----
#pragma unroll
        for (int w = 0; w < 4; ++w) {
            const int m = 8 >> w;
            const float cz = trig[w][2], sz = trig[w][3];
#pragma unroll
            for (int k = 0; k < 16; ++k) {
                const float r = re[k], q = im[k];
                if (k & m) { re[k] = r * cz - q * sz; im[k] = q * cz + r * sz; }
                else       { re[k] = r * cz + q * sz; im[k] = q * cz - r * sz; }
            }
        }
#pragma unroll
        for (int w = 0; w < 3; ++w) {
            const int cm = 8 >> w, tm = 4 >> w;
#pragma unroll
            for (int b = 0; b < 16; ++b) {
                if ((b & cm) && !(b & tm)) {
                    const int j = b | tm;
                    float t = re[b]; re[b] = re[j]; re[j] = t;
                    t = im[b]; im[b] = im[j]; im[j] = t;
                }
            }
        }

        // ---- layers 1, 2 (layer-2 RZ dropped: probability-invariant) ----
#pragma unroll
        for (int l = 1; l < 3; ++l) {
#pragma unroll
            for (int w = 0; w < 4; ++w) {
                const int m = 8 >> w, g = l * 4 + w;
                const float cy = trig[g][0], sy = trig[g][1];
#pragma unroll
                for (int b = 0; b < 16; ++b) {
                    if (b & m) continue;
                    const int j = b | m;
                    const float r0 = re[b], r1 = re[j];
                    const float i0 = im[b], i1 = im[j];
                    re[b] = cy * r0 - sy * r1;  re[j] = sy * r0 + cy * r1;
                    im[b] = cy * i0 - sy * i1;  im[j] = sy * i0 + cy * i1;
                }
                if (l != 2) {
                    const float cz = trig[g][2], sz = trig[g][3];
#pragma unroll
                    for (int k = 0; k < 16; ++k) {
                        const float r = re[k], q = im[k];
                        if (k & m) { re[k] = r * cz - q * sz; im[k] = q * cz + r * sz; }
                        else       { re[k] = r * cz + q * sz; im[k] = q * cz - r * sz; }
                    }
                }
            }
#pragma unroll
            for (int w = 0; w < 3; ++w) {
                const int cm = 8 >> w, tm = 4 >> w;
#pragma unroll
                for (int b = 0; b < 16; ++b) {
                    if ((b & cm) && !(b & tm)) {
                        const int j = b | tm;
                        float t = re[b]; re[b] = re[j]; re[j] = t;
                        t = im[b]; im[b] = im[j]; im[j] = t;
                    }
                }
            }
        }

        float ev0 = 0.f, ev1 = 0.f, ev2 = 0.f, ev3 = 0.f;
#pragma unroll
        for (int k = 0; k < 16; ++k) {
            const float pk = re[k] * re[k] + im[k] * im[k];
            ev0 += (k & 8) ? -pk : pk;
            ev1 += (k & 4) ? -pk : pk;
            ev2 += (k & 2) ? -pk : pk;
            ev3 += (k & 1) ? -pk : pk;
        }
        bufA[tid][0] = ev0; bufA[tid][1] = ev1;
        bufA[tid][2] = ev2; bufA[tid][3] = ev3;
    }
    __syncthreads();

    // ---- invert evaluation map mode-by-mode ----
    // nodes {0, pi/2, pi} -> rows (1,1,0),(1,0,1),(1,-1,0);
    // Minv = [[.5,0,.5],[.5,0,-.5],[-.5,1,-.5]]
    const float Minv[3][3] = {{0.5f, 0.0f, 0.5f},
                              {0.5f, 0.0f, -0.5f},
                              {-0.5f, 1.0f, -0.5f}};
    const int strides[4] = {27, 9, 3, 1};
#pragma unroll
    for (int mo = 0; mo < 4; ++mo) {
        const int st = strides[mo];
        float (*src)[4] = (mo & 1) ? bufB : bufA;
        float (*dst)[4] = (mo & 1) ? bufA : bufB;
        for (int idx = tid; idx < 324; idx += blockDim.x) {
            const int w = idx & 3, pos = idx >> 2;
            const int dm = (pos / st) % 3;
            const int base = pos - dm * st;
            const float v = Minv[dm][0] * src[base][w]
                          + Minv[dm][1] * src[base + st][w]
                          + Minv[dm][2] * src[base + 2 * st][w];
            if (mo == 3) {
                ws[pos * 4 + w] = v;    // quad layout (T0,T1,T2,T3)[pos]
            } else {
                dst[pos][w] = v;
            }
        }
        __syncthreads();
    }
}

__global__ __launch_bounds__(256) void vqc_main(const float* __restrict__ patch,
                                                const float* __restrict__ params,
                                                const float* __restrict__ ws,
                                                float* __restrict__ out,
                                                const int B) {
    const int i = blockIdx.x * blockDim.x + threadIdx.x;
    if (i >= B) return;

    const float4 p = reinterpret_cast<const float4*>(patch)[i];

    float c0, s0, c1, s1, c2, s2, c3, s3;
    __sincosf(p.x + params[0], &s0, &c0);
    __sincosf(p.y + params[2], &s1, &c1);
    __sincosf(p.z + params[4], &s2, &c2);
    __sincosf(p.w + params[6], &s3, &c3);

    float v01[9], v23[9];
    v01[0] = 1.0f; v01[1] = c1;      v01[2] = s1;
    v01[3] = c0;   v01[4] = c0 * c1; v01[5] = c0 * s1;
    v01[6] = s0;   v01[7] = s0 * c1; v01[8] = s0 * s1;
    v23[0] = 1.0f; v23[1] = c3;      v23[2] = s3;
    v23[3] = c2;   v23[4] = c2 * c3; v23[5] = c2 * s3;
    v23[6] = s2;   v23[7] = s2 * c3; v23[8] = s2 * s3;

    // uniform-address quad loads: 81 dwordx4 per wave-element (was 162 x8B)
    const v4f* __restrict__ Tq = reinterpret_cast<const v4f*>(ws);

    v2f o01 = {0.f, 0.f}, o23 = {0.f, 0.f};
#pragma unroll
    for (int a = 0; a < 9; ++a) {
        v2f y01 = {0.f, 0.f}, y23 = {0.f, 0.f};
#pragma unroll
        for (int b = 0; b < 9; ++b) {
            const v4f t = Tq[9 * a + b];
            const v2f ta = {t.x, t.y};       // (T0,T1)[pos]
            const v2f tb = {t.z, t.w};       // (T2,T3)[pos]
            y01 += ta * v23[b];              // v_pk_fma_f32
            y23 += tb * v23[b];
        }
        o01 += v01[a] * y01;
        o23 += v01[a] * y23;
    }

    reinterpret_cast<float4*>(out)[i] = make_float4(o01.x, o01.y, o23.x, o23.y);
}

extern "C" void kernel_launch(void* const* d_in, const int* in_sizes, int n_in,
                              void* d_out, int out_size, void* d_ws, size_t ws_size,
                              hipStream_t stream) {
    const float* patch  = (const float*)d_in[0];
    const float* params = (const float*)d_in[1];
    float* out = (float*)d_out;
    float* ws  = (float*)d_ws;
    const int B = in_sizes[0] / 4;

    vqc_setup<<<1, 384, 0, stream>>>(params, ws);

    const int block = 256;
    const int grid = (B + block - 1) / block;
    vqc_main<<<grid, block, 0, stream>>>(patch, params, ws, out, B);
}